// Round 3
// baseline (391.239 us; speedup 1.0000x reference)
//
#include <hip/hip_runtime.h>
#include <hip/hip_bf16.h>
#include <math.h>

#define B_ROWS 16384
#define C_COLS 1000
#define C_PAD  1024
#define FDIM   1024
#define NBM    128            // 16384/128 row-groups
#define FBLKS  4096           // feature normalize blocks (4 rows each)

typedef __attribute__((ext_vector_type(8))) short bf16x8;
typedef __attribute__((ext_vector_type(4))) float f32x4;

// async global->LDS, 16B per lane; lds dst is wave-uniform base (HW puts lane i at base + i*16)
#define GLD_LDS(gp, lp) __builtin_amdgcn_global_load_lds( \
    (__attribute__((address_space(1))) void*)(gp),        \
    (__attribute__((address_space(3))) void*)(lp), 16, 0, 0)

// ---------------- fused row L2-normalize fp32 -> bf16 (one wave per row) ----------------
// blocks [0, FBLKS)           -> features rows
// blocks [FBLKS, FBLKS+256)   -> prototype rows (zero-pad rows >= 1000)
__global__ __launch_bounds__(256) void normalize_all(
    const float* __restrict__ feat, const float* __restrict__ prot,
    __hip_bfloat16* __restrict__ fb, __hip_bfloat16* __restrict__ pb)
{
    const int lane = threadIdx.x & 63;
    const int wave = threadIdx.x >> 6;

    const float* in;
    __hip_bfloat16* out;
    int row, nvalid;
    if (blockIdx.x < FBLKS) {
        row = blockIdx.x * 4 + wave;  in = feat; out = fb; nvalid = B_ROWS;
    } else {
        row = (blockIdx.x - FBLKS) * 4 + wave;  in = prot; out = pb; nvalid = C_COLS;
    }
    __hip_bfloat16* orow = out + (size_t)row * FDIM;

    if (row >= nvalid) {               // zero-pad prototype rows 1000..1023
        ushort4 z = make_ushort4(0, 0, 0, 0);
        #pragma unroll
        for (int c = 0; c < 4; ++c) ((ushort4*)orow)[lane + c * 64] = z;
        return;
    }

    const float4* rp = (const float4*)(in + (size_t)row * FDIM);
    float4 v[4];
    float ss = 0.0f;
    #pragma unroll
    for (int c = 0; c < 4; ++c) {
        v[c] = rp[lane + c * 64];
        ss += v[c].x * v[c].x + v[c].y * v[c].y + v[c].z * v[c].z + v[c].w * v[c].w;
    }
    #pragma unroll
    for (int off = 1; off < 64; off <<= 1) ss += __shfl_xor(ss, off, 64);
    const float inv = 1.0f / sqrtf(fmaxf(ss, 1e-24f));

    #pragma unroll
    for (int c = 0; c < 4; ++c) {
        __hip_bfloat16 o[4];
        o[0] = __float2bfloat16(v[c].x * inv);
        o[1] = __float2bfloat16(v[c].y * inv);
        o[2] = __float2bfloat16(v[c].z * inv);
        o[3] = __float2bfloat16(v[c].w * inv);
        ((ushort4*)orow)[lane + c * 64] = *(ushort4*)o;
    }
}

// ---------------- bf16 GEMM + distance epilogue + fused last-block finalize ----------------
// LDS tile [128 rows][64 k], row stride 64 elems (128 B); logical ksub k at phys slot (k ^ (row&7))
__global__ __launch_bounds__(256) void gemm_dist(
    const __hip_bfloat16* __restrict__ A,
    const __hip_bfloat16* __restrict__ Bp,
    __hip_bfloat16* __restrict__ D,
    float* __restrict__ rowsum,
    int* __restrict__ cnt,
    const float* __restrict__ scale, const float* __restrict__ temp,
    float* __restrict__ out)
{
    __shared__ __hip_bfloat16 As[128 * 64];   // 16 KB
    __shared__ __hip_bfloat16 Bs[128 * 64];   // 16 KB
    __shared__ int amLast;

    const int tid  = threadIdx.x;
    const int lane = tid & 63;
    const int wave = tid >> 6;

    // XCD swizzle: all 8 bn-blocks of one bm share id%8 (same XCD) for A/D L2 locality
    const int id  = blockIdx.x;             // 0..1023
    const int xcd = id & 7;
    const int seq = id >> 3;                // 0..127
    const int bn  = seq & 7;                // 0..7
    const int bm  = xcd * 16 + (seq >> 3);  // 0..127

    const int waveM = (wave >> 1) * 64;
    const int waveN = (wave & 1) * 64;

    f32x4 acc[4][4] = {};

    // staging: chunk = 8 rows x 64 k (1 KB); lane i -> row i>>3, phys slot i&7,
    // fetches logical ksub = (i&7) ^ ((i>>3)&7)
    const int srow  = lane >> 3;
    const int sksub = (lane & 7) ^ (srow & 7);
    const __hip_bfloat16* Abase = A  + ((size_t)(bm * 128) + srow) * FDIM + sksub * 8;
    const __hip_bfloat16* Bbase = Bp + ((size_t)(bn * 128) + srow) * FDIM + sksub * 8;

    #pragma unroll 1
    for (int k0 = 0; k0 < FDIM; k0 += 64) {
        __syncthreads();
        #pragma unroll
        for (int c4 = 0; c4 < 4; ++c4) {
            const int chunk = wave * 4 + c4;               // 0..15
            GLD_LDS(Abase + (size_t)(chunk * 8) * FDIM + k0, &As[chunk * 512]);
            GLD_LDS(Bbase + (size_t)(chunk * 8) * FDIM + k0, &Bs[chunk * 512]);
        }
        __syncthreads();

        #pragma unroll
        for (int h = 0; h < 2; ++h) {
            bf16x8 a[4], b[4];
            const int q = h * 4 + (lane >> 4);             // logical ksub 0..7
            #pragma unroll
            for (int mt = 0; mt < 4; ++mt) {
                const int R = waveM + mt * 16 + (lane & 15);
                a[mt] = *(const bf16x8*)&As[R * 64 + ((q ^ (R & 7)) * 8)];
            }
            #pragma unroll
            for (int nt = 0; nt < 4; ++nt) {
                const int R = waveN + nt * 16 + (lane & 15);
                b[nt] = *(const bf16x8*)&Bs[R * 64 + ((q ^ (R & 7)) * 8)];
            }
            #pragma unroll
            for (int mt = 0; mt < 4; ++mt)
                #pragma unroll
                for (int nt = 0; nt < 4; ++nt)
                    acc[mt][nt] = __builtin_amdgcn_mfma_f32_16x16x32_bf16(a[mt], b[nt], acc[mt][nt], 0, 0, 0);
        }
    }

    // epilogue: d = sqrt(max(1 - sim, 0)); C/D layout: col = lane&15, row = (lane>>4)*4 + reg
    const int row0 = bm * 128 + waveM;
    const int col0 = bn * 128 + waveN;
    #pragma unroll
    for (int mt = 0; mt < 4; ++mt) {
        #pragma unroll
        for (int r = 0; r < 4; ++r) {
            const int row = row0 + mt * 16 + (lane >> 4) * 4 + r;
            float part = 0.0f;
            #pragma unroll
            for (int nt = 0; nt < 4; ++nt) {
                const int col = col0 + nt * 16 + (lane & 15);
                const float sim = acc[mt][nt][r];
                const float dv = sqrtf(fmaxf(1.0f - sim, 0.0f));
                if (col < C_COLS) {
                    D[(size_t)row * C_COLS + col] = __float2bfloat16(dv);
                    part += dv;
                }
            }
            part += __shfl_xor(part, 1, 64);
            part += __shfl_xor(part, 2, 64);
            part += __shfl_xor(part, 4, 64);
            part += __shfl_xor(part, 8, 64);
            if ((lane & 15) == 0) atomicAdd(&rowsum[row], part);
        }
    }

    // ---- last-block-done election: 8th bn block of this bm finalizes the row-group ----
    __threadfence();                       // release: D stores + rowsum atomics visible device-wide
    __syncthreads();
    if (tid == 0) amLast = (atomicAdd(&cnt[bm], 1) == 7);
    __syncthreads();
    if (!amLast) return;
    __threadfence();                       // acquire: see other blocks' D / rowsum

    const float a = -fabsf(scale[0]) / temp[0];
    // finalize rows [bm*128, bm*128+128) x 1000 cols; 8 cols per thread-iter
    for (int g = tid; g < 128 * 125; g += 256) {
        const int r   = g / 125;
        const int c8  = g - r * 125;
        const int row = bm * 128 + r;
        const float m = rowsum[row] * (1.0f / (float)C_COLS);
        const bf16x8 dv = *(const bf16x8*)(D + (size_t)row * C_COLS + c8 * 8);
        const __hip_bfloat16* dp = (const __hip_bfloat16*)&dv;
        float4 o0, o1;
        o0.x = a * (__bfloat162float(dp[0]) + m);
        o0.y = a * (__bfloat162float(dp[1]) + m);
        o0.z = a * (__bfloat162float(dp[2]) + m);
        o0.w = a * (__bfloat162float(dp[3]) + m);
        o1.x = a * (__bfloat162float(dp[4]) + m);
        o1.y = a * (__bfloat162float(dp[5]) + m);
        o1.z = a * (__bfloat162float(dp[6]) + m);
        o1.w = a * (__bfloat162float(dp[7]) + m);
        float4* op = (float4*)(out + (size_t)row * C_COLS + c8 * 8);
        op[0] = o0;
        op[1] = o1;
    }
}

extern "C" void kernel_launch(void* const* d_in, const int* in_sizes, int n_in,
                              void* d_out, int out_size, void* d_ws, size_t ws_size,
                              hipStream_t stream)
{
    const float* features = (const float*)d_in[0];   // [16384,1024]
    const float* protos   = (const float*)d_in[1];   // [1000,1024]
    const float* dscale   = (const float*)d_in[2];   // [1]
    const float* temp     = (const float*)d_in[3];   // [1]
    float* out = (float*)d_out;                      // [16384,1000]

    char* ws = (char*)d_ws;
    __hip_bfloat16* fb = (__hip_bfloat16*)ws;                     // 33,554,432 B
    __hip_bfloat16* pb = (__hip_bfloat16*)(ws + 33554432);        //  2,097,152 B
    __hip_bfloat16* D  = (__hip_bfloat16*)(ws + 35651584);        // 32,768,000 B
    float* rowsum      = (float*)(ws + 68419584);                 //     65,536 B
    int*   cnt         = (int*)  (ws + 68485120);                 //        512 B

    // one memset covers rowsum + cnt (contiguous)
    hipMemsetAsync(rowsum, 0, B_ROWS * sizeof(float) + NBM * sizeof(int), stream);

    normalize_all<<<FBLKS + C_PAD / 4, 256, 0, stream>>>(features, protos, fb, pb);

    gemm_dist<<<1024, 256, 0, stream>>>(fb, pb, D, rowsum, cnt, dscale, temp, out);
}

// Round 4
// 188.576 us; speedup vs baseline: 2.0747x; 2.0747x over previous
//
#include <hip/hip_runtime.h>
#include <hip/hip_bf16.h>
#include <math.h>

#define B_ROWS 16384
#define C_COLS 1000
#define C_PAD  1024
#define FDIM   1024
#define FBLKS  4096           // feature normalize blocks (4 rows each)

typedef __attribute__((ext_vector_type(8)))  short bf16x8;   // 4 VGPRs: A/B frag
typedef __attribute__((ext_vector_type(16))) float f32x16;   // 16 VGPRs: 32x32 acc

// async global->LDS, 16B per lane; lds dst is wave-uniform base (HW puts lane i at base + i*16)
#define GLD_LDS(gp, lp) __builtin_amdgcn_global_load_lds( \
    (__attribute__((address_space(1))) void*)(gp),        \
    (__attribute__((address_space(3))) void*)(lp), 16, 0, 0)

// ---------------- fused row L2-normalize fp32 -> bf16 (one wave per row) ----------------
__global__ __launch_bounds__(256) void normalize_all(
    const float* __restrict__ feat, const float* __restrict__ prot,
    __hip_bfloat16* __restrict__ fb, __hip_bfloat16* __restrict__ pb)
{
    const int lane = threadIdx.x & 63;
    const int wave = threadIdx.x >> 6;

    const float* in;
    __hip_bfloat16* out;
    int row, nvalid;
    if (blockIdx.x < FBLKS) {
        row = blockIdx.x * 4 + wave;  in = feat; out = fb; nvalid = B_ROWS;
    } else {
        row = (blockIdx.x - FBLKS) * 4 + wave;  in = prot; out = pb; nvalid = C_COLS;
    }
    __hip_bfloat16* orow = out + (size_t)row * FDIM;

    if (row >= nvalid) {               // zero-pad prototype rows 1000..1023
        ushort4 z = make_ushort4(0, 0, 0, 0);
        #pragma unroll
        for (int c = 0; c < 4; ++c) ((ushort4*)orow)[lane + c * 64] = z;
        return;
    }

    const float4* rp = (const float4*)(in + (size_t)row * FDIM);
    float4 v[4];
    float ss = 0.0f;
    #pragma unroll
    for (int c = 0; c < 4; ++c) {
        v[c] = rp[lane + c * 64];
        ss += v[c].x * v[c].x + v[c].y * v[c].y + v[c].z * v[c].z + v[c].w * v[c].w;
    }
    #pragma unroll
    for (int off = 1; off < 64; off <<= 1) ss += __shfl_xor(ss, off, 64);
    const float inv = 1.0f / sqrtf(fmaxf(ss, 1e-24f));

    #pragma unroll
    for (int c = 0; c < 4; ++c) {
        __hip_bfloat16 o[4];
        o[0] = __float2bfloat16(v[c].x * inv);
        o[1] = __float2bfloat16(v[c].y * inv);
        o[2] = __float2bfloat16(v[c].z * inv);
        o[3] = __float2bfloat16(v[c].w * inv);
        ((ushort4*)orow)[lane + c * 64] = *(ushort4*)o;
    }
}

// ---------------- bf16 GEMM 256x128 block tile, 32x32x16 MFMA + distance epilogue ----------
// LDS: A tile [256 rows][64 k], B tile [128 rows][64 k]; row stride 64 elems (128 B).
// Logical k-octet o stored at phys slot (o ^ (row&7)) -> ds_read_b128 conflict-free.
__global__ __launch_bounds__(256, 2) void gemm_dist(
    const __hip_bfloat16* __restrict__ A,
    const __hip_bfloat16* __restrict__ Bp,
    __hip_bfloat16* __restrict__ D,
    float* __restrict__ rowsum)
{
    __shared__ __hip_bfloat16 As[256 * 64];   // 32 KB
    __shared__ __hip_bfloat16 Bs[128 * 64];   // 16 KB

    const int tid  = threadIdx.x;
    const int lane = tid & 63;
    const int wave = tid >> 6;

    // XCD swizzle: the 8 bn-blocks of one bm-group are consecutive in seq on one XCD
    const int id  = blockIdx.x;             // 0..511
    const int xcd = id & 7;
    const int seq = id >> 3;                // 0..63
    const int bn  = seq & 7;                // 0..7
    const int bmg = xcd * 8 + (seq >> 3);   // 0..63 -> rows [bmg*256, +256)

    const int waveM = (wave >> 1) * 128;    // 0 or 128 (within 256-row A tile)
    const int waveN = (wave & 1) * 64;      // 0 or 64  (within 128-row B tile)

    f32x16 acc[4][2] = {};                  // 4 M-tiles x 2 N-tiles of 32x32

    // staging: chunk = 8 rows x 64 k (1 KB). lane i -> row i>>3, phys slot i&7,
    // fetching logical octet (i&7) ^ (row&7). A = chunks 0..31, B = chunks 32..47.
    const int srow  = lane >> 3;
    const int sksub = (lane & 7) ^ (srow & 7);
    const __hip_bfloat16* Abase = A  + ((size_t)(bmg * 256) + srow) * FDIM + sksub * 8;
    const __hip_bfloat16* Bbase = Bp + ((size_t)(bn  * 128) + srow) * FDIM + sksub * 8;

    #pragma unroll 1
    for (int k0 = 0; k0 < FDIM; k0 += 64) {
        __syncthreads();
        #pragma unroll
        for (int j = 0; j < 12; ++j) {
            const int c = wave * 12 + j;               // 0..47, wave-uniform
            if (c < 32) GLD_LDS(Abase + (size_t)(c * 8) * FDIM + k0, &As[c * 512]);
            else        GLD_LDS(Bbase + (size_t)((c - 32) * 8) * FDIM + k0, &Bs[(c - 32) * 512]);
        }
        __syncthreads();

        #pragma unroll
        for (int s = 0; s < 4; ++s) {                  // four k-steps of 16
            const int oct = s * 2 + (lane >> 5);       // logical k-octet 0..7
            bf16x8 b[2];
            #pragma unroll
            for (int nt = 0; nt < 2; ++nt) {
                const int R = waveN + nt * 32 + (lane & 31);
                b[nt] = *(const bf16x8*)&Bs[R * 64 + ((oct ^ (R & 7)) * 8)];
            }
            #pragma unroll
            for (int mt = 0; mt < 4; ++mt) {
                const int R = waveM + mt * 32 + (lane & 31);
                const bf16x8 a = *(const bf16x8*)&As[R * 64 + ((oct ^ (R & 7)) * 8)];
                acc[mt][0] = __builtin_amdgcn_mfma_f32_32x32x16_bf16(a, b[0], acc[mt][0], 0, 0, 0);
                acc[mt][1] = __builtin_amdgcn_mfma_f32_32x32x16_bf16(a, b[1], acc[mt][1], 0, 0, 0);
            }
        }
    }

    // epilogue: d = sqrt(max(1-sim,0)).
    // 32x32 C/D: col = lane&31, row = (r&3) + 8*(r>>2) + 4*(lane>>5)
    const int row0 = bmg * 256 + waveM;
    const int col0 = bn * 128 + waveN;
    #pragma unroll
    for (int mt = 0; mt < 4; ++mt) {
        #pragma unroll
        for (int r = 0; r < 16; ++r) {
            const int row = row0 + mt * 32 + (r & 3) + 8 * (r >> 2) + 4 * (lane >> 5);
            float part = 0.0f;
            #pragma unroll
            for (int nt = 0; nt < 2; ++nt) {
                const int col = col0 + nt * 32 + (lane & 31);
                const float sim = acc[mt][nt][r];
                const float dv = sqrtf(fmaxf(1.0f - sim, 0.0f));
                if (col < C_COLS) {
                    D[(size_t)row * C_COLS + col] = __float2bfloat16(dv);
                    part += dv;
                }
            }
            // reduce across the 32 lanes of this half (rows differ between halves)
            part += __shfl_xor(part, 1, 64);
            part += __shfl_xor(part, 2, 64);
            part += __shfl_xor(part, 4, 64);
            part += __shfl_xor(part, 8, 64);
            part += __shfl_xor(part, 16, 64);
            if ((lane & 31) == 0) atomicAdd(&rowsum[row], part);
        }
    }
}

// ---------------- finalize: out = (-|ds|/T) * (d + rowsum/1000) ----------------
__global__ __launch_bounds__(256) void finalize(
    const __hip_bfloat16* __restrict__ D, const float* __restrict__ rowsum,
    const float* __restrict__ scale, const float* __restrict__ temp,
    float* __restrict__ out)
{
    const size_t i = (size_t)blockIdx.x * 256 + threadIdx.x;   // 8-element group
    const float a = -fabsf(scale[0]) / temp[0];
    const int row = (int)((i * 8) / C_COLS);                   // 1000 % 8 == 0, no straddle
    const float m = rowsum[row] * (1.0f / (float)C_COLS);

    const bf16x8 dv = *(const bf16x8*)(D + i * 8);
    const __hip_bfloat16* dp = (const __hip_bfloat16*)&dv;
    float4 o0, o1;
    o0.x = a * (__bfloat162float(dp[0]) + m);
    o0.y = a * (__bfloat162float(dp[1]) + m);
    o0.z = a * (__bfloat162float(dp[2]) + m);
    o0.w = a * (__bfloat162float(dp[3]) + m);
    o1.x = a * (__bfloat162float(dp[4]) + m);
    o1.y = a * (__bfloat162float(dp[5]) + m);
    o1.z = a * (__bfloat162float(dp[6]) + m);
    o1.w = a * (__bfloat162float(dp[7]) + m);
    ((float4*)out)[i * 2]     = o0;
    ((float4*)out)[i * 2 + 1] = o1;
}

extern "C" void kernel_launch(void* const* d_in, const int* in_sizes, int n_in,
                              void* d_out, int out_size, void* d_ws, size_t ws_size,
                              hipStream_t stream)
{
    const float* features = (const float*)d_in[0];   // [16384,1024]
    const float* protos   = (const float*)d_in[1];   // [1000,1024]
    const float* dscale   = (const float*)d_in[2];   // [1]
    const float* temp     = (const float*)d_in[3];   // [1]
    float* out = (float*)d_out;                      // [16384,1000]

    char* ws = (char*)d_ws;
    __hip_bfloat16* fb = (__hip_bfloat16*)ws;                     // 33,554,432 B
    __hip_bfloat16* pb = (__hip_bfloat16*)(ws + 33554432);        //  2,097,152 B
    __hip_bfloat16* D  = (__hip_bfloat16*)(ws + 35651584);        // 32,768,000 B
    float* rowsum      = (float*)(ws + 68419584);                 //     65,536 B

    hipMemsetAsync(rowsum, 0, B_ROWS * sizeof(float), stream);

    normalize_all<<<FBLKS + C_PAD / 4, 256, 0, stream>>>(features, protos, fb, pb);

    gemm_dist<<<512, 256, 0, stream>>>(fb, pb, D, rowsum);

    finalize<<<(B_ROWS * C_COLS / 8) / 256, 256, 0, stream>>>(D, rowsum, dscale, temp, out);
}